// Round 10
// baseline (277.383 us; speedup 1.0000x reference)
//
#include <hip/hip_runtime.h>
#include <math.h>

#define NTOK   262144
#define DIM    1024
#define NEXP   64
#define TOPK   8
#define WROWS  32           // rows per wave (2 m-tiles)
#define ROWS   64           // rows per block = 2 waves x 32 rows
#define BLK    128
#define NSLAB  16           // slabs of 64 floats (256 B/row) = 2 MFMA K-steps
#define BUFSZ  8192         // 32 rows x 256 B
#define SLICE  (3 * BUFSZ)  // per-wave triple-buffered slabs; scores [32][65] alias

#define OFF_IDX ((size_t)NTOK * TOPK)
#define OFF_USE (2 * (size_t)NTOK * TOPK)
#define OFF_TOT (OFF_USE + NEXP)

typedef __attribute__((ext_vector_type(8))) short bf16x8;
typedef __attribute__((ext_vector_type(4))) float f32x4;

union FragU { bf16x8 v; unsigned int u[4]; };

// pack 8 f32 (a=k0..3, b=k4..7) -> bf16x8 fragment (truncate)
__device__ __forceinline__ bf16x8 pack_bf16(float4 a, float4 b) {
    FragU r;
    r.u[0] = (__float_as_uint(a.x) >> 16) | (__float_as_uint(a.y) & 0xFFFF0000u);
    r.u[1] = (__float_as_uint(a.z) >> 16) | (__float_as_uint(a.w) & 0xFFFF0000u);
    r.u[2] = (__float_as_uint(b.x) >> 16) | (__float_as_uint(b.y) & 0xFFFF0000u);
    r.u[3] = (__float_as_uint(b.z) >> 16) | (__float_as_uint(b.w) & 0xFFFF0000u);
    return r.v;
}

// W [64][1024] f32 -> bf16 MFMA B-fragments in d_ws:
//   wf[((kc*4+nt)*64 + lane)*8 + j] = bf16(W[nt*16+(lane&15)][kc*32+(lane>>4)*8+j])
// kc = global K-step 0..31. Also init usage counters + total_tokens.
__global__ __launch_bounds__(256) void gate_prep_kernel(const float* __restrict__ W,
                                                        unsigned short* __restrict__ wf,
                                                        float* __restrict__ out) {
    int idx = blockIdx.x * 256 + threadIdx.x;      // 65536 total
    int j    = idx & 7;
    int lane = (idx >> 3) & 63;
    int nt   = (idx >> 9) & 3;
    int kc   = idx >> 11;
    int fq = lane >> 4, fr = lane & 15;
    float v = W[(size_t)(nt * 16 + fr) * DIM + kc * 32 + fq * 8 + j];
    unsigned int u = __float_as_uint(v);
    u += 0x7FFFu + ((u >> 16) & 1u);               // RNE to bf16
    wf[idx] = (unsigned short)(u >> 16);

    if (blockIdx.x == 0) {
        if (threadIdx.x < NEXP) out[OFF_USE + threadIdx.x] = 0.0f;
        if (threadIdx.x == NEXP) out[OFF_TOT] = (float)((size_t)NTOK * TOPK);
    }
}

__global__ __launch_bounds__(BLK) void gate_kernel(const float* __restrict__ x,
                                                   const unsigned short* __restrict__ wf,
                                                   const float* __restrict__ bias,
                                                   float* __restrict__ out) {
    // Per-wave private slices -> NO barriers in the K-loop, counted vmcnt only.
    // vs round 9, single physical change: stage granule 128 B -> 256 B per row
    // (slab = 2 K-steps), so each x-row is visited 16x256B instead of 32x128B.
    // Kept: NT staging, stage depth-2 (triple-buffered slabs), K-phase rotation.
    __shared__ __align__(16) char smem[2 * SLICE];
    __shared__ float hist[NEXP];

    const int tid  = threadIdx.x;
    const int w    = tid >> 6;
    const int lane = tid & 63;
    const int fq   = lane >> 4;   // 0..3
    const int fr   = lane & 15;   // 0..15
    const size_t rowBase = (size_t)blockIdx.x * ROWS;

    if (tid < NEXP) hist[tid] = 0.0f;

    char* myslice = smem + w * SLICE;

    // Staging: 32 rows x 256 B per buffer (8 KB), 8 instrs x 1 KB.
    // Instr i, lane l: flat = i*64+l; row = flat>>4 (0..31), phys 16B-unit
    // p = flat&15; SOURCE pre-swizzled (u = p ^ (row&15)) so the linear LDS
    // dest yields the swizzled layout (both-sides-or-neither rule). Each
    // instr covers 4 rows x 256 B fully contiguous.
    const char* xb = (const char*)(x + (rowBase + (size_t)w * WROWS) * DIM);
    const char* src[8];
#pragma unroll
    for (int i = 0; i < 8; i++) {
        int flat = i * 64 + lane;
        int row = flat >> 4;
        int u = (flat & 15) ^ (row & 15);
        src[i] = xb + (size_t)row * (DIM * 4) + u * 16;
    }

#define STAGE(BUF, sp)                                                            \
    do {                                                                          \
        _Pragma("unroll")                                                         \
        for (int i_ = 0; i_ < 8; i_++)                                            \
            __builtin_amdgcn_global_load_lds(                                     \
                (const __attribute__((address_space(1))) unsigned int*)(src[i_] + (size_t)(sp) * 256), \
                (__attribute__((address_space(3))) unsigned int*)(myslice + (BUF) * BUFSZ + i_ * 1024), \
                16, 0, 2 /* NT streaming read */);                                \
    } while (0)

    // A-fragment ds_read slot indices (16B units in an 8KB buffer):
    // K-step kk (0,1), m-tile mt, half h: row = mt*16+fr,
    // logical unit = kk*8 + fq*2 + h, slot = row*16 + (unit ^ fr)
    int aslot[2][2][2];
#pragma unroll
    for (int kk = 0; kk < 2; kk++)
#pragma unroll
        for (int mt = 0; mt < 2; mt++)
#pragma unroll
            for (int h = 0; h < 2; h++)
                aslot[kk][mt][h] = (mt * 16 + fr) * 16 + ((kk * 8 + fq * 2 + h) ^ fr);

    const bf16x8* wfv = (const bf16x8*)wf;

    f32x4 acc[2][4] = {};   // [mt][nt]
    bf16x8 bcur[8];         // [kk*4+nt] for the current slab

    // K-phase rotation start (16 slab-offsets x 256 B cover the full 4KB row)
    const int sp0 = ((int)blockIdx.x + (w << 3)) & 15;

    // Prologue FIFO: bfrag(sp0):8 | stage(sp0):8 | stage(sp0+1):8 -> 24 outstanding
#pragma unroll
    for (int f = 0; f < 8; f++) bcur[f] = wfv[(size_t)(sp0 * 8 + f) * 64 + lane];
    __builtin_amdgcn_sched_barrier(0);
    STAGE(0, sp0);
    STAGE(1, (sp0 + 1) & 15);

    // Step s: issue bfrag(s+1):8 FIRST (L2-fast), then stage(s+2):8; then
    // wait vmcnt(24) -> drains exactly [stage(s), bfrag(s)] (stage issued two
    // steps ago: depth 2). FIFO check at step s, oldest->newest:
    // [st(s)8, bf(s)8, st(s+1)8, bf(s+1)8, st(s+2)8] = 40 -> keep 24. Never 0.
#define GSTEP(SP, BUF, SBUF, MODE)                                                \
    {                                                                             \
        const int sp_ = (SP);                                                     \
        bf16x8 bnext[8];                                                          \
        if ((MODE) >= 1) {                                                        \
            const int sn_ = (sp_ + 1) & 15;                                       \
            _Pragma("unroll")                                                     \
            for (int f = 0; f < 8; f++)                                           \
                bnext[f] = wfv[(size_t)(sn_ * 8 + f) * 64 + lane];                \
            __builtin_amdgcn_sched_barrier(0);                                    \
        }                                                                         \
        if ((MODE) == 2) STAGE(SBUF, (sp_ + 2) & 15);                             \
        if ((MODE) == 2)      asm volatile("s_waitcnt vmcnt(24)" ::: "memory");   \
        else if ((MODE) == 1) asm volatile("s_waitcnt vmcnt(16)" ::: "memory");   \
        else                  asm volatile("s_waitcnt vmcnt(0)" ::: "memory");    \
        __builtin_amdgcn_sched_barrier(0);                                        \
        const float4* xt = (const float4*)(myslice + (BUF) * BUFSZ);              \
        _Pragma("unroll")                                                         \
        for (int kk = 0; kk < 2; kk++) {                                          \
            _Pragma("unroll")                                                     \
            for (int mt = 0; mt < 2; mt++) {                                      \
                bf16x8 af = pack_bf16(xt[aslot[kk][mt][0]], xt[aslot[kk][mt][1]]); \
                _Pragma("unroll")                                                 \
                for (int nt = 0; nt < 4; nt++)                                    \
                    acc[mt][nt] = __builtin_amdgcn_mfma_f32_16x16x32_bf16(af, bcur[kk * 4 + nt], acc[mt][nt], 0, 0, 0); \
            }                                                                     \
        }                                                                         \
        if ((MODE) >= 1) {                                                        \
            _Pragma("unroll")                                                     \
            for (int f = 0; f < 8; f++) bcur[f] = bnext[f];                       \
        }                                                                         \
    }

#pragma unroll 1
    for (int t = 0; t < 4; t++) {             // steps 0..11, buf = step%3
        GSTEP((sp0 + 3 * t) & 15,     0, 2, 2);
        GSTEP((sp0 + 3 * t + 1) & 15, 1, 0, 2);
        GSTEP((sp0 + 3 * t + 2) & 15, 2, 1, 2);
    }
    GSTEP((sp0 + 12) & 15, 0, 2, 2);          // stages slab 14
    GSTEP((sp0 + 13) & 15, 1, 0, 2);          // stages slab 15
    GSTEP((sp0 + 14) & 15, 2, 0, 1);          // waits [st(14), bf(14)]
    GSTEP((sp0 + 15) & 15, 0, 0, 0);          // drains

    // scores (+bias) -> own slice, [32 rows][65] f32 (aliases own stage bufs;
    // own DMA done via final vmcnt(0)).  C/D layout: col = fr, row = fq*4 + r.
    float* sw = (float*)myslice;
    float bv[4];
#pragma unroll
    for (int nt = 0; nt < 4; nt++) bv[nt] = bias[nt * 16 + fr];
#pragma unroll
    for (int mt = 0; mt < 2; mt++) {
        int mbase = mt * 16 + fq * 4;
#pragma unroll
        for (int nt = 0; nt < 4; nt++) {
            int n = nt * 16 + fr;
#pragma unroll
            for (int r = 0; r < 4; r++)
                sw[(mbase + r) * 65 + n] = acc[mt][nt][r] + bv[nt];
        }
    }
    __syncthreads();   // the only block-wide barrier

    // epilogue: one thread per row (threads 0..63)
    if (tid < ROWS) {
        const float* rp = (const float*)(smem + (tid >> 5) * SLICE) + (tid & 31) * 65;

        // top-8 on RAW scores (exp monotone; strict > keeps ascending index
        // order among ties, matching lax.top_k)
        float tv[8]; int ti[8];
#pragma unroll
        for (int k = 0; k < 8; k++) { tv[k] = -1e30f; ti[k] = 0; }

#pragma unroll 4
        for (int e = 0; e < NEXP; e++) {
            float s = rp[e];
#pragma unroll
            for (int k = 7; k >= 1; k--) {
                bool up   = s > tv[k - 1];
                bool here = s > tv[k];
                float nv = up ? tv[k - 1] : (here ? s : tv[k]);
                int   ni = up ? ti[k - 1] : (here ? e : ti[k]);
                tv[k] = nv; ti[k] = ni;
            }
            bool c0 = s > tv[0];
            ti[0] = c0 ? e : ti[0];
            tv[0] = c0 ? s : tv[0];
        }
        float m = tv[0];   // row max

        float sum = 0.0f;
#pragma unroll 8
        for (int e = 0; e < NEXP; e++) sum += __expf(rp[e] - m);
        float rinv = 1.0f / sum;

        float wv_[8];
#pragma unroll
        for (int k = 0; k < 8; k++) wv_[k] = __expf(tv[k] - m) * rinv;

        size_t ro = (rowBase + tid) * TOPK;
        *(float4*)(out + ro)     = make_float4(wv_[0], wv_[1], wv_[2], wv_[3]);
        *(float4*)(out + ro + 4) = make_float4(wv_[4], wv_[5], wv_[6], wv_[7]);
        *(float4*)(out + OFF_IDX + ro)     = make_float4((float)ti[0], (float)ti[1], (float)ti[2], (float)ti[3]);
        *(float4*)(out + OFF_IDX + ro + 4) = make_float4((float)ti[4], (float)ti[5], (float)ti[6], (float)ti[7]);
#pragma unroll
        for (int k = 0; k < 8; k++) atomicAdd(&hist[ti[k]], 1.0f);
    }
    __syncthreads();
    if (tid < NEXP) atomicAdd(&out[OFF_USE + tid], hist[tid]);
}

extern "C" void kernel_launch(void* const* d_in, const int* in_sizes, int n_in,
                              void* d_out, int out_size, void* d_ws, size_t ws_size,
                              hipStream_t stream) {
    const float* x    = (const float*)d_in[0];
    const float* W    = (const float*)d_in[1];
    const float* bias = (const float*)d_in[2];
    float* out = (float*)d_out;
    unsigned short* wf = (unsigned short*)d_ws;   // 128 KB fragment-ordered bf16 W

    gate_prep_kernel<<<256, 256, 0, stream>>>(W, wf, out);
    gate_kernel<<<NTOK / ROWS, BLK, 0, stream>>>(x, wf, bias, out);
}